// Round 10
// baseline (88.206 us; speedup 1.0000x reference)
//
#include <hip/hip_runtime.h>
#include <hip/hip_bf16.h>

typedef __bf16 bf16x8 __attribute__((ext_vector_type(8)));
typedef __bf16 bf16x4 __attribute__((ext_vector_type(4)));
typedef float  f32x4  __attribute__((ext_vector_type(4)));

#define HF 128          // hidden dim
#define W1K 256         // W1 inner dim (2H)

// ========== Kernel 0: one-time repack W1 fp32 -> bf16 MFMA-A-fragment order
// wf layout: [h][f=mt*4+kk][lane][8 bf16]; frag = W[h][mt*16+l15][kk*32+lg*8..+8]
__global__ __launch_bounds__(256) void w1_repack(
    const float* __restrict__ W1, __bf16* __restrict__ wf)
{
    const int h    = blockIdx.x;        // 0 -> A (u), 1 -> B (v)
    const int tid  = threadIdx.x;
    const int lane = tid & 63;
    const int wid  = tid >> 6;
    const int l15  = lane & 15;
    const int lg   = lane >> 4;

    for (int f = wid; f < 32; f += 4) {
        const int mt = f >> 2;
        const int kk = f & 3;
        const float* p = W1 + h * HF + (size_t)(mt * 16 + l15) * W1K
                       + kk * 32 + lg * 8;
        f32x4 a = *reinterpret_cast<const f32x4*>(p);
        f32x4 b = *reinterpret_cast<const f32x4*>(p + 4);
        bf16x8 w8;
        #pragma unroll
        for (int i = 0; i < 4; ++i) {
            w8[i]     = (__bf16)a[i];
            w8[i + 4] = (__bf16)b[i];
        }
        *reinterpret_cast<bf16x8*>(wf + ((size_t)(h * 32 + f) * 64 + lane) * 8) = w8;
    }
}

// ========== Kernel 1 (v11): async DMA pipeline with COUNTED vmcnt ==========
// u[n] = A . x_src[n],  v[n] = B . x_dst[n]   (b1 added in k2)
// R9 finding: __syncthreads between tiles drains vmcnt(0), serializing each
// tile to issue+latency+transfer (~8.8K cy/tile vs 3.2K transfer). Fix (T4):
// per iter  STAGE ld(t+1)[8] -> compute(t) -> store(t)[8] ->
//           s_waitcnt vmcnt(8)  (8 newest = stores; ld(t+1) guaranteed done,
//           stores never drained) -> raw s_barrier.
// Load latency hides under compute; steady state is HBM-transfer-bound.
__global__ __launch_bounds__(256, 1) void node_precompute11(
    const float* __restrict__ x_src, const float* __restrict__ x_dst,
    const __bf16* __restrict__ wf,
    __bf16* __restrict__ u, __bf16* __restrict__ v, int nNodes)
{
    __shared__ __align__(16) __bf16 wlds[2][32][64][8];   // 64 KiB
    __shared__ __align__(16) float  xlds[2][64 * HF];     // 2 x 32 KiB

    const int tid  = threadIdx.x;
    const int lane = tid & 63;
    const int wid  = tid >> 6;      // 0..3
    const int l15  = lane & 15;
    const int lg   = lane >> 4;

    // stage pre-packed W (both halves): pure 16-B copies, L3-hot
    {
        __bf16* wl = &wlds[0][0][0][0];
        for (int c = tid; c < 4096; c += 256) {
            bf16x8 w8 = *reinterpret_cast<const bf16x8*>(wf + (size_t)c * 8);
            *reinterpret_cast<bf16x8*>(wl + (size_t)c * 8) = w8;
        }
    }

    const int nth = (nNodes + 63) >> 6;     // 64-node tiles per half
    const int T   = nth * 2;                // tile t: h = t&1, trow = t>>1

    // ---- async stage: tile t -> xlds[buf] (linear dest, swizzled source) --
    auto STAGE = [&](int buf, int t) {
        const int h    = t & 1;
        const int trow = t >> 1;
        const float* __restrict__ xp = h ? x_dst : x_src;
        #pragma unroll
        for (int i = 0; i < 8; ++i) {
            const int G   = i * 256 + tid;          // 16-B granule 0..2047
            const int row = G >> 5;                  // 0..63
            const int q   = G & 31;
            const int qs  = q ^ (row & 7);           // inverse swizzle on src
            const int grow = min(trow * 64 + row, nNodes - 1);
            const float* src = xp + (size_t)grow * HF + qs * 4;
            __builtin_amdgcn_global_load_lds(
                (const __attribute__((address_space(1))) void*)src,
                (__attribute__((address_space(3))) void*)&xlds[buf][(size_t)G * 4],
                16, 0, 0);
        }
    };

    int t = blockIdx.x;
    if (t >= T) return;
    STAGE(0, t);
    __syncthreads();        // prologue: full drain once

    int buf = 0;
    while (t < T) {
        const int tn = t + gridDim.x;
        const bool more = (tn < T);
        if (more) STAGE(buf ^ 1, tn);    // ld(t+1): 8 vmem ops

        // ---- compute tile t from xlds[buf] ----
        const int h    = t & 1;
        const int trow = t >> 1;
        const int row  = wid * 16 + l15;             // 0..63
        const int node = trow * 64 + row;

        f32x4 acc[8];
        #pragma unroll
        for (int mt = 0; mt < 8; ++mt) acc[mt] = (f32x4){0.f, 0.f, 0.f, 0.f};

        const float* xr = &xlds[buf][(size_t)row * HF];
        #pragma unroll
        for (int kk = 0; kk < 4; ++kk) {
            const int q0 = kk * 8 + lg * 2;
            f32x4 a0 = *reinterpret_cast<const f32x4*>(xr + ((q0)     ^ (row & 7)) * 4);
            f32x4 a1 = *reinterpret_cast<const f32x4*>(xr + ((q0 + 1) ^ (row & 7)) * 4);
            bf16x8 xb;
            #pragma unroll
            for (int i = 0; i < 4; ++i) {
                xb[i]     = (__bf16)a0[i];
                xb[i + 4] = (__bf16)a1[i];
            }
            #pragma unroll
            for (int mt = 0; mt < 8; ++mt) {
                bf16x8 wa = *reinterpret_cast<const bf16x8*>(&wlds[h][mt * 4 + kk][lane][0]);
                acc[mt] = __builtin_amdgcn_mfma_f32_16x16x32_bf16(
                    wa, xb, acc[mt], 0, 0, 0);
            }
        }

        if (node < nNodes) {             // st(t): 8 vmem ops (newest)
            __bf16* op = (h ? v : u) + (size_t)node * HF + lg * 4;
            #pragma unroll
            for (int mt = 0; mt < 8; ++mt) {
                bf16x4 o4;
                #pragma unroll
                for (int r = 0; r < 4; ++r) o4[r] = (__bf16)acc[mt][r];
                *reinterpret_cast<bf16x4*>(op + mt * 16) = o4;
            }
        }

        if (more) {
            // newest 8 outstanding = our stores; everything older (incl.
            // ld(t+1)) must complete. Stores are never drained in-loop.
            asm volatile("s_waitcnt vmcnt(8)" ::: "memory");
            __builtin_amdgcn_sched_barrier(0);
            __builtin_amdgcn_s_barrier();
            __builtin_amdgcn_sched_barrier(0);
        }
        buf ^= 1;
        t = tn;
    }
}

// ================= Kernel 2: per-edge score (pure gather) =================
// score[e] = W2 . relu(u[src[e]] + v[dst[e]] + b1) + b2
__global__ __launch_bounds__(256) void edge_score_kernel(
    const __bf16* __restrict__ u, const __bf16* __restrict__ v,
    const int* __restrict__ sidx, const int* __restrict__ didx,
    const float* __restrict__ W2, const float* __restrict__ b1,
    const float* __restrict__ b2,
    float* __restrict__ out, int nEdges)
{
    const int tid = threadIdx.x;
    const int sub = tid >> 4;        // 0..15
    const int l16 = tid & 15;

    const int ebase = blockIdx.x * 64 + sub;   // edges ebase + {0,16,32,48}

    float w2v[8], b1v[8];
    #pragma unroll
    for (int j = 0; j < 8; ++j) {
        w2v[j] = W2[l16 * 8 + j];
        b1v[j] = b1[l16 * 8 + j];
    }
    const float b2v = b2[0];

    int e[4], si[4], di[4];
    #pragma unroll
    for (int q = 0; q < 4; ++q) {
        e[q] = ebase + q * 16;
        const int c = min(e[q], nEdges - 1);
        si[q] = sidx[c];
        di[q] = didx[c];
    }

    bf16x8 uv[4], vv[4];
    #pragma unroll
    for (int q = 0; q < 4; ++q) {
        uv[q] = *reinterpret_cast<const bf16x8*>(u + (size_t)si[q] * HF + l16 * 8);
        vv[q] = *reinterpret_cast<const bf16x8*>(v + (size_t)di[q] * HF + l16 * 8);
    }

    float s[4] = {0.f, 0.f, 0.f, 0.f};
    #pragma unroll
    for (int q = 0; q < 4; ++q)
        #pragma unroll
        for (int j = 0; j < 8; ++j)
            s[q] += fmaxf((float)uv[q][j] + (float)vv[q][j] + b1v[j], 0.f) * w2v[j];

    #pragma unroll
    for (int off = 1; off < 16; off <<= 1)
        #pragma unroll
        for (int q = 0; q < 4; ++q)
            s[q] += __shfl_xor(s[q], off, 64);

    if (l16 == 0) {
        #pragma unroll
        for (int q = 0; q < 4; ++q)
            if (e[q] < nEdges) out[e[q]] = s[q] + b2v;
    }
}

// ================= Fallback: fused single kernel (round-1) =================
__global__ __launch_bounds__(256, 2) void edge_mlp_kernel(
    const float* __restrict__ x_src, const float* __restrict__ x_dst,
    const int*   __restrict__ src_idx, const int* __restrict__ dst_idx,
    const float* __restrict__ W1, const float* __restrict__ b1,
    const float* __restrict__ W2, const float* __restrict__ b2,
    float* __restrict__ out, int nEdges)
{
    __shared__ __align__(16) __bf16 w1lds[64 * 64 * 8];

    const int tid  = threadIdx.x;
    const int lane = tid & 63;
    const int wid  = tid >> 6;
    const int l15  = lane & 15;
    const int lg   = lane >> 4;

    for (int p = wid; p < 64; p += 4) {
        const int n   = p >> 3;
        const int kk  = p & 7;
        const float* src = W1 + (n * 16 + l15) * W1K + kk * 32 + lg * 8;
        bf16x8 w8;
        #pragma unroll
        for (int i = 0; i < 8; ++i) w8[i] = (__bf16)src[i];
        *reinterpret_cast<bf16x8*>(&w1lds[(p * 64 + lane) * 8]) = w8;
    }
    __syncthreads();

    float w2v[8], b1v[8];
    #pragma unroll
    for (int n = 0; n < 8; ++n) {
        w2v[n] = W2[n * 16 + l15];
        b1v[n] = b1[n * 16 + l15];
    }
    const float b2v = b2[0];

    const int ntiles = nEdges / 256;
    for (int t = blockIdx.x; t < ntiles; t += gridDim.x) {
        const int ebase = t * 256 + wid * 64;

        const float* srow[4];
        const float* drow[4];
        #pragma unroll
        for (int m = 0; m < 4; ++m) {
            const int e  = ebase + m * 16 + l15;
            srow[m] = x_src + (size_t)src_idx[e] * HF + lg * 8;
            drow[m] = x_dst + (size_t)dst_idx[e] * HF + lg * 8;
        }

        f32x4 acc[4][8];
        #pragma unroll
        for (int m = 0; m < 4; ++m)
            #pragma unroll
            for (int n = 0; n < 8; ++n)
                acc[m][n] = (f32x4){0.f, 0.f, 0.f, 0.f};

        #pragma unroll
        for (int kk = 0; kk < 8; ++kk) {
            bf16x8 a[4];
            #pragma unroll
            for (int m = 0; m < 4; ++m) {
                const float* p = (kk < 4) ? (srow[m] + kk * 32)
                                          : (drow[m] + (kk - 4) * 32);
                f32x4 u0 = *reinterpret_cast<const f32x4*>(p);
                f32x4 u1 = *reinterpret_cast<const f32x4*>(p + 4);
                bf16x8 av;
                #pragma unroll
                for (int i = 0; i < 4; ++i) {
                    av[i]     = (__bf16)u0[i];
                    av[i + 4] = (__bf16)u1[i];
                }
                a[m] = av;
            }
            #pragma unroll
            for (int n = 0; n < 8; ++n) {
                bf16x8 bfrag = *reinterpret_cast<const bf16x8*>(
                    &w1lds[((n * 8 + kk) * 64 + lane) * 8]);
                #pragma unroll
                for (int m = 0; m < 4; ++m) {
                    acc[m][n] = __builtin_amdgcn_mfma_f32_16x16x32_bf16(
                        a[m], bfrag, acc[m][n], 0, 0, 0);
                }
            }
        }

        #pragma unroll
        for (int m = 0; m < 4; ++m) {
            float part[4];
            #pragma unroll
            for (int r = 0; r < 4; ++r) {
                float s = 0.f;
                #pragma unroll
                for (int n = 0; n < 8; ++n) {
                    float hv = acc[m][n][r] + b1v[n];
                    s += fmaxf(hv, 0.f) * w2v[n];
                }
                part[r] = s;
            }
            #pragma unroll
            for (int off = 1; off < 16; off <<= 1) {
                #pragma unroll
                for (int r = 0; r < 4; ++r)
                    part[r] += __shfl_xor(part[r], off, 64);
            }
            if (l15 == m) {
                f32x4 v4 = { part[0] + b2v, part[1] + b2v,
                             part[2] + b2v, part[3] + b2v };
                *reinterpret_cast<f32x4*>(&out[ebase + m * 16 + lg * 4]) = v4;
            }
        }
    }
}

extern "C" void kernel_launch(void* const* d_in, const int* in_sizes, int n_in,
                              void* d_out, int out_size, void* d_ws, size_t ws_size,
                              hipStream_t stream) {
    const float* x_src  = (const float*)d_in[0];
    const float* x_dst  = (const float*)d_in[1];
    const int*   sidx   = (const int*)d_in[2];
    const int*   didx   = (const int*)d_in[3];
    const float* W1     = (const float*)d_in[4];
    const float* b1     = (const float*)d_in[5];
    const float* W2     = (const float*)d_in[6];
    const float* b2     = (const float*)d_in[7];
    float* out = (float*)d_out;

    const int nEdges = in_sizes[2];
    const int nNodes = in_sizes[0] / HF;

    const size_t uvsz   = (size_t)2 * nNodes * HF;                  // elems
    const size_t needed = uvsz * sizeof(__bf16) + 64 * 1024;        // u+v+wf
    if (ws_size >= needed) {
        __bf16* u  = (__bf16*)d_ws;
        __bf16* v  = u + (size_t)nNodes * HF;
        __bf16* wf = u + uvsz;

        w1_repack<<<2, 256, 0, stream>>>(W1, wf);

        node_precompute11<<<256, 256, 0, stream>>>(
            x_src, x_dst, wf, u, v, nNodes);

        const int egrid = (nEdges + 63) / 64;
        edge_score_kernel<<<egrid, 256, 0, stream>>>(
            u, v, sidx, didx, W2, b1, b2, out, nEdges);
    } else {
        edge_mlp_kernel<<<512, 256, 0, stream>>>(
            x_src, x_dst, sidx, didx, W1, b1, W2, b2, out, nEdges);
    }
}

// Round 11
// 83.865 us; speedup vs baseline: 1.0518x; 1.0518x over previous
//
#include <hip/hip_runtime.h>
#include <hip/hip_bf16.h>

typedef __bf16 bf16x8 __attribute__((ext_vector_type(8)));
typedef __bf16 bf16x4 __attribute__((ext_vector_type(4)));
typedef float  f32x4  __attribute__((ext_vector_type(4)));

#define HF 128          // hidden dim
#define W1K 256         // W1 inner dim (2H)

// ========== Kernel 0: one-time repack W1 fp32 -> bf16 MFMA-A-fragment order
// wf layout: [h][f=mt*4+kk][lane][8 bf16]; frag = W[h][mt*16+l15][kk*32+lg*8..+8]
__global__ __launch_bounds__(256) void w1_repack(
    const float* __restrict__ W1, __bf16* __restrict__ wf)
{
    const int h    = blockIdx.x;        // 0 -> A (u), 1 -> B (v)
    const int tid  = threadIdx.x;
    const int lane = tid & 63;
    const int wid  = tid >> 6;
    const int l15  = lane & 15;
    const int lg   = lane >> 4;

    for (int f = wid; f < 32; f += 4) {
        const int mt = f >> 2;
        const int kk = f & 3;
        const float* p = W1 + h * HF + (size_t)(mt * 16 + l15) * W1K
                       + kk * 32 + lg * 8;
        f32x4 a = *reinterpret_cast<const f32x4*>(p);
        f32x4 b = *reinterpret_cast<const f32x4*>(p + 4);
        bf16x8 w8;
        #pragma unroll
        for (int i = 0; i < 4; ++i) {
            w8[i]     = (__bf16)a[i];
            w8[i + 4] = (__bf16)b[i];
        }
        *reinterpret_cast<bf16x8*>(wf + ((size_t)(h * 32 + f) * 64 + lane) * 8) = w8;
    }
}

// ====== Kernel 1 (v12): barrier-free wave-private DMA pipelines ============
// u[n] = A . x_src[n],  v[n] = B . x_dst[n]   (b1 added in k2)
// R10 finding: counted vmcnt + shared barrier changed nothing -> the binding
// constraint was 4 lockstep waves (1/SIMD, convoy on the block barrier).
// v12: 8 waves (2/SIMD), each wave owns an 8-node double-buffered private
// LDS tile (2x4KB); per-tile 4 global_load_lds(next) -> s_waitcnt vmcnt(12)
// (outstanding = 4 cur loads [oldest] + 8 stores + 4 new loads -> drains
// exactly the cur-tile loads; per-wave counter, NO barriers at all) ->
// compute -> 8 stores. Two waves/SIMD cover each other's stalls.
__global__ __launch_bounds__(512, 1) void node_precompute12(
    const float* __restrict__ x_src, const float* __restrict__ x_dst,
    const __bf16* __restrict__ wf,
    __bf16* __restrict__ u, __bf16* __restrict__ v, int nNodes)
{
    __shared__ __align__(16) __bf16 wlds[2][32][64][8];   // 64 KiB (shared W)
    __shared__ __align__(16) float  xlds[8][2][1024];     // 8 waves x 2 x 4 KiB

    const int tid  = threadIdx.x;
    const int lane = tid & 63;
    const int wid  = tid >> 6;      // 0..7
    const int l15  = lane & 15;
    const int lg   = lane >> 4;

    // stage pre-packed W (both halves): pure 16-B copies, L3-hot
    {
        __bf16* wl = &wlds[0][0][0][0];
        for (int c = tid; c < 4096; c += 512) {
            bf16x8 w8 = *reinterpret_cast<const bf16x8*>(wf + (size_t)c * 8);
            *reinterpret_cast<bf16x8*>(wl + (size_t)c * 8) = w8;
        }
    }
    __syncthreads();   // once; steady state is barrier-free

    const int nst = (nNodes + 7) >> 3;      // 12500 8-node subtiles per half
    const int T   = nst * 2;                // task: h = t&1, trow = t>>1
    const int stride = gridDim.x * 8;

    // ---- async stage: task t -> xlds[wid][buf] (4 x 16B per lane) --------
    // granule G = i*64+lane in [0,256): row = G>>5 (0..7), q = G&31.
    // linear LDS dest; source column pre-swizzled q^row (rule 21).
    auto STAGE = [&](int buf, int t) {
        const int h    = t & 1;
        const int trow = t >> 1;
        const float* __restrict__ xp = h ? x_dst : x_src;
        #pragma unroll
        for (int i = 0; i < 4; ++i) {
            const int G   = i * 64 + lane;
            const int row = G >> 5;
            const int q   = G & 31;
            const int qs  = q ^ row;                 // rows 0..7: full XOR
            const int grow = min(trow * 8 + row, nNodes - 1);
            const float* src = xp + (size_t)grow * HF + qs * 4;
            __builtin_amdgcn_global_load_lds(
                (const __attribute__((address_space(1))) void*)src,
                (__attribute__((address_space(3))) void*)&xlds[wid][buf][(size_t)G * 4],
                16, 0, 0);
        }
    };

    int t = (blockIdx.x * 8 + wid);
    if (t >= T) return;
    STAGE(0, t);

    int buf = 0;
    const int row_l = l15 & 7;     // lanes 8..15 alias rows 0..7 (loads only)
    while (t < T) {
        const int tn = t + stride;
        if (tn < T) STAGE(buf ^ 1, tn);

        // wait for cur-tile loads (oldest 4): <=12 outstanding remain
        asm volatile("s_waitcnt vmcnt(12)" ::: "memory");
        __builtin_amdgcn_sched_barrier(0);

        const int h    = t & 1;
        const int trow = t >> 1;

        f32x4 acc[8];
        #pragma unroll
        for (int mt = 0; mt < 8; ++mt) acc[mt] = (f32x4){0.f, 0.f, 0.f, 0.f};

        const float* xr = &xlds[wid][buf][(size_t)row_l * 128];
        #pragma unroll
        for (int kk = 0; kk < 4; ++kk) {
            const int q0 = kk * 8 + lg * 2;
            f32x4 a0 = *reinterpret_cast<const f32x4*>(xr + ((q0)     ^ row_l) * 4);
            f32x4 a1 = *reinterpret_cast<const f32x4*>(xr + ((q0 + 1) ^ row_l) * 4);
            bf16x8 xb;
            #pragma unroll
            for (int i = 0; i < 4; ++i) {
                xb[i]     = (__bf16)a0[i];
                xb[i + 4] = (__bf16)a1[i];
            }
            #pragma unroll
            for (int mt = 0; mt < 8; ++mt) {
                bf16x8 wa = *reinterpret_cast<const bf16x8*>(&wlds[h][mt * 4 + kk][lane][0]);
                acc[mt] = __builtin_amdgcn_mfma_f32_16x16x32_bf16(
                    wa, xb, acc[mt], 0, 0, 0);
            }
        }

        // store: node col = l15 (only 0..7 valid), channels mt*16 + lg*4
        const int node = trow * 8 + l15;
        if (l15 < 8 && node < nNodes) {
            __bf16* op = (h ? v : u) + (size_t)node * HF + lg * 4;
            #pragma unroll
            for (int mt = 0; mt < 8; ++mt) {
                bf16x4 o4;
                #pragma unroll
                for (int r = 0; r < 4; ++r) o4[r] = (__bf16)acc[mt][r];
                *reinterpret_cast<bf16x4*>(op + mt * 16) = o4;
            }
        }

        buf ^= 1;
        t = tn;
    }
}

// ================= Kernel 2: per-edge score (pure gather) =================
// score[e] = W2 . relu(u[src[e]] + v[dst[e]] + b1) + b2
__global__ __launch_bounds__(256) void edge_score_kernel(
    const __bf16* __restrict__ u, const __bf16* __restrict__ v,
    const int* __restrict__ sidx, const int* __restrict__ didx,
    const float* __restrict__ W2, const float* __restrict__ b1,
    const float* __restrict__ b2,
    float* __restrict__ out, int nEdges)
{
    const int tid = threadIdx.x;
    const int sub = tid >> 4;        // 0..15
    const int l16 = tid & 15;

    const int ebase = blockIdx.x * 64 + sub;   // edges ebase + {0,16,32,48}

    float w2v[8], b1v[8];
    #pragma unroll
    for (int j = 0; j < 8; ++j) {
        w2v[j] = W2[l16 * 8 + j];
        b1v[j] = b1[l16 * 8 + j];
    }
    const float b2v = b2[0];

    int e[4], si[4], di[4];
    #pragma unroll
    for (int q = 0; q < 4; ++q) {
        e[q] = ebase + q * 16;
        const int c = min(e[q], nEdges - 1);
        si[q] = sidx[c];
        di[q] = didx[c];
    }

    bf16x8 uv[4], vv[4];
    #pragma unroll
    for (int q = 0; q < 4; ++q) {
        uv[q] = *reinterpret_cast<const bf16x8*>(u + (size_t)si[q] * HF + l16 * 8);
        vv[q] = *reinterpret_cast<const bf16x8*>(v + (size_t)di[q] * HF + l16 * 8);
    }

    float s[4] = {0.f, 0.f, 0.f, 0.f};
    #pragma unroll
    for (int q = 0; q < 4; ++q)
        #pragma unroll
        for (int j = 0; j < 8; ++j)
            s[q] += fmaxf((float)uv[q][j] + (float)vv[q][j] + b1v[j], 0.f) * w2v[j];

    #pragma unroll
    for (int off = 1; off < 16; off <<= 1)
        #pragma unroll
        for (int q = 0; q < 4; ++q)
            s[q] += __shfl_xor(s[q], off, 64);

    if (l16 == 0) {
        #pragma unroll
        for (int q = 0; q < 4; ++q)
            if (e[q] < nEdges) out[e[q]] = s[q] + b2v;
    }
}

// ================= Fallback: fused single kernel (round-1) =================
__global__ __launch_bounds__(256, 2) void edge_mlp_kernel(
    const float* __restrict__ x_src, const float* __restrict__ x_dst,
    const int*   __restrict__ src_idx, const int* __restrict__ dst_idx,
    const float* __restrict__ W1, const float* __restrict__ b1,
    const float* __restrict__ W2, const float* __restrict__ b2,
    float* __restrict__ out, int nEdges)
{
    __shared__ __align__(16) __bf16 w1lds[64 * 64 * 8];

    const int tid  = threadIdx.x;
    const int lane = tid & 63;
    const int wid  = tid >> 6;
    const int l15  = lane & 15;
    const int lg   = lane >> 4;

    for (int p = wid; p < 64; p += 4) {
        const int n   = p >> 3;
        const int kk  = p & 7;
        const float* src = W1 + (n * 16 + l15) * W1K + kk * 32 + lg * 8;
        bf16x8 w8;
        #pragma unroll
        for (int i = 0; i < 8; ++i) w8[i] = (__bf16)src[i];
        *reinterpret_cast<bf16x8*>(&w1lds[(p * 64 + lane) * 8]) = w8;
    }
    __syncthreads();

    float w2v[8], b1v[8];
    #pragma unroll
    for (int n = 0; n < 8; ++n) {
        w2v[n] = W2[n * 16 + l15];
        b1v[n] = b1[n * 16 + l15];
    }
    const float b2v = b2[0];

    const int ntiles = nEdges / 256;
    for (int t = blockIdx.x; t < ntiles; t += gridDim.x) {
        const int ebase = t * 256 + wid * 64;

        const float* srow[4];
        const float* drow[4];
        #pragma unroll
        for (int m = 0; m < 4; ++m) {
            const int e  = ebase + m * 16 + l15;
            srow[m] = x_src + (size_t)src_idx[e] * HF + lg * 8;
            drow[m] = x_dst + (size_t)dst_idx[e] * HF + lg * 8;
        }

        f32x4 acc[4][8];
        #pragma unroll
        for (int m = 0; m < 4; ++m)
            #pragma unroll
            for (int n = 0; n < 8; ++n)
                acc[m][n] = (f32x4){0.f, 0.f, 0.f, 0.f};

        #pragma unroll
        for (int kk = 0; kk < 8; ++kk) {
            bf16x8 a[4];
            #pragma unroll
            for (int m = 0; m < 4; ++m) {
                const float* p = (kk < 4) ? (srow[m] + kk * 32)
                                          : (drow[m] + (kk - 4) * 32);
                f32x4 u0 = *reinterpret_cast<const f32x4*>(p);
                f32x4 u1 = *reinterpret_cast<const f32x4*>(p + 4);
                bf16x8 av;
                #pragma unroll
                for (int i = 0; i < 4; ++i) {
                    av[i]     = (__bf16)u0[i];
                    av[i + 4] = (__bf16)u1[i];
                }
                a[m] = av;
            }
            #pragma unroll
            for (int n = 0; n < 8; ++n) {
                bf16x8 bfrag = *reinterpret_cast<const bf16x8*>(
                    &w1lds[((n * 8 + kk) * 64 + lane) * 8]);
                #pragma unroll
                for (int m = 0; m < 4; ++m) {
                    acc[m][n] = __builtin_amdgcn_mfma_f32_16x16x32_bf16(
                        a[m], bfrag, acc[m][n], 0, 0, 0);
                }
            }
        }

        #pragma unroll
        for (int m = 0; m < 4; ++m) {
            float part[4];
            #pragma unroll
            for (int r = 0; r < 4; ++r) {
                float s = 0.f;
                #pragma unroll
                for (int n = 0; n < 8; ++n) {
                    float hv = acc[m][n][r] + b1v[n];
                    s += fmaxf(hv, 0.f) * w2v[n];
                }
                part[r] = s;
            }
            #pragma unroll
            for (int off = 1; off < 16; off <<= 1) {
                #pragma unroll
                for (int r = 0; r < 4; ++r)
                    part[r] += __shfl_xor(part[r], off, 64);
            }
            if (l15 == m) {
                f32x4 v4 = { part[0] + b2v, part[1] + b2v,
                             part[2] + b2v, part[3] + b2v };
                *reinterpret_cast<f32x4*>(&out[ebase + m * 16 + lg * 4]) = v4;
            }
        }
    }
}

extern "C" void kernel_launch(void* const* d_in, const int* in_sizes, int n_in,
                              void* d_out, int out_size, void* d_ws, size_t ws_size,
                              hipStream_t stream) {
    const float* x_src  = (const float*)d_in[0];
    const float* x_dst  = (const float*)d_in[1];
    const int*   sidx   = (const int*)d_in[2];
    const int*   didx   = (const int*)d_in[3];
    const float* W1     = (const float*)d_in[4];
    const float* b1     = (const float*)d_in[5];
    const float* W2     = (const float*)d_in[6];
    const float* b2     = (const float*)d_in[7];
    float* out = (float*)d_out;

    const int nEdges = in_sizes[2];
    const int nNodes = in_sizes[0] / HF;

    const size_t uvsz   = (size_t)2 * nNodes * HF;                  // elems
    const size_t needed = uvsz * sizeof(__bf16) + 64 * 1024;        // u+v+wf
    if (ws_size >= needed) {
        __bf16* u  = (__bf16*)d_ws;
        __bf16* v  = u + (size_t)nNodes * HF;
        __bf16* wf = u + uvsz;

        w1_repack<<<2, 256, 0, stream>>>(W1, wf);

        node_precompute12<<<256, 512, 0, stream>>>(
            x_src, x_dst, wf, u, v, nNodes);

        const int egrid = (nEdges + 63) / 64;
        edge_score_kernel<<<egrid, 256, 0, stream>>>(
            u, v, sidx, didx, W2, b1, b2, out, nEdges);
    } else {
        edge_mlp_kernel<<<512, 256, 0, stream>>>(
            x_src, x_dst, sidx, didx, W1, b1, W2, b2, out, nEdges);
    }
}

// Round 12
// 82.219 us; speedup vs baseline: 1.0728x; 1.0200x over previous
//
#include <hip/hip_runtime.h>
#include <hip/hip_bf16.h>

typedef __bf16 bf16x8 __attribute__((ext_vector_type(8)));
typedef __bf16 bf16x4 __attribute__((ext_vector_type(4)));
typedef float  f32x4  __attribute__((ext_vector_type(4)));

#define HF 128          // hidden dim
#define W1K 256         // W1 inner dim (2H)

// ========== Kernel 0: one-time repack W1 fp32 -> bf16 MFMA-A-fragment order
// wf layout: [h][f=mt*4+kk][lane][8 bf16]; frag = W[h][mt*16+l15][kk*32+lg*8..+8]
__global__ __launch_bounds__(256) void w1_repack(
    const float* __restrict__ W1, __bf16* __restrict__ wf)
{
    const int h    = blockIdx.x;        // 0 -> A (u), 1 -> B (v)
    const int tid  = threadIdx.x;
    const int lane = tid & 63;
    const int wid  = tid >> 6;
    const int l15  = lane & 15;
    const int lg   = lane >> 4;

    for (int f = wid; f < 32; f += 4) {
        const int mt = f >> 2;
        const int kk = f & 3;
        const float* p = W1 + h * HF + (size_t)(mt * 16 + l15) * W1K
                       + kk * 32 + lg * 8;
        f32x4 a = *reinterpret_cast<const f32x4*>(p);
        f32x4 b = *reinterpret_cast<const f32x4*>(p + 4);
        bf16x8 w8;
        #pragma unroll
        for (int i = 0; i < 4; ++i) {
            w8[i]     = (__bf16)a[i];
            w8[i + 4] = (__bf16)b[i];
        }
        *reinterpret_cast<bf16x8*>(wf + ((size_t)(h * 32 + f) * 64 + lane) * 8) = w8;
    }
}

// ====== Kernel 1 (v13): reg-resident W + barrier-free private DMA pipes ====
// u[n] = A . x_src[n],  v[n] = B . x_dst[n]   (b1 added in k2)
// R11 finding: v12 was LDS-BW-bound: 32KB W re-read per 4KB x tile ~= 93%
// of the 112 B/cy LDS ceiling. v13: W in 128 VGPRs (loaded once; (512,1)
// -> 2 waves/SIMD -> 256-VGPR cap, ~200 used, no spill), 16-node private
// tiles (all 16 MFMA B-cols used; x LDS reads 1:1). Barrier-free; counted
// vmcnt per wave: prologue vmcnt(0) once; steady vmcnt(16) (24 outstanding =
// 8 cur loads + 8 prev stores + 8 next loads); final iter vmcnt(8).
__global__ __launch_bounds__(512, 1) void node_precompute13(
    const float* __restrict__ x_src, const float* __restrict__ x_dst,
    const __bf16* __restrict__ wf,
    __bf16* __restrict__ u, __bf16* __restrict__ v, int nNodes)
{
    __shared__ __align__(16) float xlds[8][2][2048];   // 8 waves x 2 x 8 KiB

    const int tid  = threadIdx.x;
    const int lane = tid & 63;
    const int wid  = tid >> 6;      // 0..7
    const int l15  = lane & 15;
    const int lg   = lane >> 4;

    const int h = wid & 1;          // waves alternate halves
    const float* __restrict__ xh = h ? x_dst : x_src;
    __bf16* __restrict__ oph = h ? v : u;

    // ---- one-time: this half's 32 W fragments into 128 VGPRs (L3-hot) ----
    bf16x8 wfrag[32];
    {
        const __bf16* wsrc = wf + ((size_t)h * 32 * 64 + lane) * 8;
        #pragma unroll
        for (int f = 0; f < 32; ++f)
            wfrag[f] = *reinterpret_cast<const bf16x8*>(wsrc + (size_t)f * 64 * 8);
    }

    const int nst    = nNodes >> 4;        // 6250 16-node subtiles (exact)
    const int stride = gridDim.x * 4;      // wave-slots per half

    // ---- async stage: subtile st -> xlds[wid][buf]; 8 x 16B per lane ----
    // granule G = i*64+lane in [0,512): row = G>>5 (0..15), q = G&31.
    // linear LDS dest; source pre-swizzled q^(row&7) (rule 21).
    auto STAGE = [&](int buf, int st) {
        #pragma unroll
        for (int i = 0; i < 8; ++i) {
            const int G   = i * 64 + lane;
            const int row = G >> 5;
            const int q   = G & 31;
            const int qs  = q ^ (row & 7);
            const int grow = min(st * 16 + row, nNodes - 1);
            const float* src = xh + (size_t)grow * HF + qs * 4;
            __builtin_amdgcn_global_load_lds(
                (const __attribute__((address_space(1))) void*)src,
                (__attribute__((address_space(3))) void*)&xlds[wid][buf][(size_t)G * 4],
                16, 0, 0);
        }
    };

    int st = blockIdx.x * 4 + (wid >> 1);
    if (st >= nst) return;
    STAGE(0, st);
    asm volatile("s_waitcnt vmcnt(0)" ::: "memory");   // wave-local, once
    __builtin_amdgcn_sched_barrier(0);

    int buf = 0;
    while (st < nst) {
        const int stn = st + stride;
        const bool more = (stn < nst);
        if (more) {
            STAGE(buf ^ 1, stn);                       // 8 new loads
            asm volatile("s_waitcnt vmcnt(16)" ::: "memory");  // cur loads done
        } else {
            asm volatile("s_waitcnt vmcnt(8)" ::: "memory");   // drain cur loads
        }
        __builtin_amdgcn_sched_barrier(0);

        f32x4 acc[8];
        #pragma unroll
        for (int mt = 0; mt < 8; ++mt) acc[mt] = (f32x4){0.f, 0.f, 0.f, 0.f};

        const float* xr = &xlds[wid][buf][(size_t)l15 * 128];
        #pragma unroll
        for (int kk = 0; kk < 4; ++kk) {
            const int q0 = kk * 8 + lg * 2;
            f32x4 a0 = *reinterpret_cast<const f32x4*>(xr + ((q0)     ^ (l15 & 7)) * 4);
            f32x4 a1 = *reinterpret_cast<const f32x4*>(xr + ((q0 + 1) ^ (l15 & 7)) * 4);
            bf16x8 xb;
            #pragma unroll
            for (int i = 0; i < 4; ++i) {
                xb[i]     = (__bf16)a0[i];
                xb[i + 4] = (__bf16)a1[i];
            }
            #pragma unroll
            for (int mt = 0; mt < 8; ++mt)
                acc[mt] = __builtin_amdgcn_mfma_f32_16x16x32_bf16(
                    wfrag[mt * 4 + kk], xb, acc[mt], 0, 0, 0);
        }

        // store: node = st*16 + l15 (exact, no tail), channels mt*16+lg*4..+4
        {
            const int node = st * 16 + l15;
            __bf16* op = oph + (size_t)node * HF + lg * 4;
            #pragma unroll
            for (int mt = 0; mt < 8; ++mt) {
                bf16x4 o4;
                #pragma unroll
                for (int r = 0; r < 4; ++r) o4[r] = (__bf16)acc[mt][r];
                *reinterpret_cast<bf16x4*>(op + mt * 16) = o4;
            }
        }

        buf ^= 1;
        st = stn;
    }
}

// ================= Kernel 2: per-edge score (pure gather, 8 edges/sub) =====
// score[e] = W2 . relu(u[src[e]] + v[dst[e]] + b1) + b2
__global__ __launch_bounds__(256) void edge_score_kernel(
    const __bf16* __restrict__ u, const __bf16* __restrict__ v,
    const int* __restrict__ sidx, const int* __restrict__ didx,
    const float* __restrict__ W2, const float* __restrict__ b1,
    const float* __restrict__ b2,
    float* __restrict__ out, int nEdges)
{
    const int tid = threadIdx.x;
    const int sub = tid >> 4;        // 0..15
    const int l16 = tid & 15;

    const int ebase = blockIdx.x * 128 + sub;  // edges ebase + q*16, q<8

    float w2v[8], b1v[8];
    #pragma unroll
    for (int j = 0; j < 8; ++j) {
        w2v[j] = W2[l16 * 8 + j];
        b1v[j] = b1[l16 * 8 + j];
    }
    const float b2v = b2[0];

    int e[8], si[8], di[8];
    #pragma unroll
    for (int q = 0; q < 8; ++q) {
        e[q] = ebase + q * 16;
        const int c = min(e[q], nEdges - 1);
        si[q] = sidx[c];
        di[q] = didx[c];
    }

    bf16x8 uv[8], vv[8];
    #pragma unroll
    for (int q = 0; q < 8; ++q) {
        uv[q] = *reinterpret_cast<const bf16x8*>(u + (size_t)si[q] * HF + l16 * 8);
        vv[q] = *reinterpret_cast<const bf16x8*>(v + (size_t)di[q] * HF + l16 * 8);
    }

    float s[8];
    #pragma unroll
    for (int q = 0; q < 8; ++q) {
        float acc = 0.f;
        #pragma unroll
        for (int j = 0; j < 8; ++j)
            acc += fmaxf((float)uv[q][j] + (float)vv[q][j] + b1v[j], 0.f) * w2v[j];
        s[q] = acc;
    }

    #pragma unroll
    for (int off = 1; off < 16; off <<= 1)
        #pragma unroll
        for (int q = 0; q < 8; ++q)
            s[q] += __shfl_xor(s[q], off, 64);

    if (l16 == 0) {
        #pragma unroll
        for (int q = 0; q < 8; ++q)
            if (e[q] < nEdges) out[e[q]] = s[q] + b2v;
    }
}

// ================= Fallback: fused single kernel (round-1) =================
__global__ __launch_bounds__(256, 2) void edge_mlp_kernel(
    const float* __restrict__ x_src, const float* __restrict__ x_dst,
    const int*   __restrict__ src_idx, const int* __restrict__ dst_idx,
    const float* __restrict__ W1, const float* __restrict__ b1,
    const float* __restrict__ W2, const float* __restrict__ b2,
    float* __restrict__ out, int nEdges)
{
    __shared__ __align__(16) __bf16 w1lds[64 * 64 * 8];

    const int tid  = threadIdx.x;
    const int lane = tid & 63;
    const int wid  = tid >> 6;
    const int l15  = lane & 15;
    const int lg   = lane >> 4;

    for (int p = wid; p < 64; p += 4) {
        const int n   = p >> 3;
        const int kk  = p & 7;
        const float* src = W1 + (n * 16 + l15) * W1K + kk * 32 + lg * 8;
        bf16x8 w8;
        #pragma unroll
        for (int i = 0; i < 8; ++i) w8[i] = (__bf16)src[i];
        *reinterpret_cast<bf16x8*>(&w1lds[(p * 64 + lane) * 8]) = w8;
    }
    __syncthreads();

    float w2v[8], b1v[8];
    #pragma unroll
    for (int n = 0; n < 8; ++n) {
        w2v[n] = W2[n * 16 + l15];
        b1v[n] = b1[n * 16 + l15];
    }
    const float b2v = b2[0];

    const int ntiles = nEdges / 256;
    for (int t = blockIdx.x; t < ntiles; t += gridDim.x) {
        const int ebase = t * 256 + wid * 64;

        const float* srow[4];
        const float* drow[4];
        #pragma unroll
        for (int m = 0; m < 4; ++m) {
            const int e  = ebase + m * 16 + l15;
            srow[m] = x_src + (size_t)src_idx[e] * HF + lg * 8;
            drow[m] = x_dst + (size_t)dst_idx[e] * HF + lg * 8;
        }

        f32x4 acc[4][8];
        #pragma unroll
        for (int m = 0; m < 4; ++m)
            #pragma unroll
            for (int n = 0; n < 8; ++n)
                acc[m][n] = (f32x4){0.f, 0.f, 0.f, 0.f};

        #pragma unroll
        for (int kk = 0; kk < 8; ++kk) {
            bf16x8 a[4];
            #pragma unroll
            for (int m = 0; m < 4; ++m) {
                const float* p = (kk < 4) ? (srow[m] + kk * 32)
                                          : (drow[m] + (kk - 4) * 32);
                f32x4 u0 = *reinterpret_cast<const f32x4*>(p);
                f32x4 u1 = *reinterpret_cast<const f32x4*>(p + 4);
                bf16x8 av;
                #pragma unroll
                for (int i = 0; i < 4; ++i) {
                    av[i]     = (__bf16)u0[i];
                    av[i + 4] = (__bf16)u1[i];
                }
                a[m] = av;
            }
            #pragma unroll
            for (int n = 0; n < 8; ++n) {
                bf16x8 bfrag = *reinterpret_cast<const bf16x8*>(
                    &w1lds[((n * 8 + kk) * 64 + lane) * 8]);
                #pragma unroll
                for (int m = 0; m < 4; ++m) {
                    acc[m][n] = __builtin_amdgcn_mfma_f32_16x16x32_bf16(
                        a[m], bfrag, acc[m][n], 0, 0, 0);
                }
            }
        }

        #pragma unroll
        for (int m = 0; m < 4; ++m) {
            float part[4];
            #pragma unroll
            for (int r = 0; r < 4; ++r) {
                float s = 0.f;
                #pragma unroll
                for (int n = 0; n < 8; ++n) {
                    float hv = acc[m][n][r] + b1v[n];
                    s += fmaxf(hv, 0.f) * w2v[n];
                }
                part[r] = s;
            }
            #pragma unroll
            for (int off = 1; off < 16; off <<= 1) {
                #pragma unroll
                for (int r = 0; r < 4; ++r)
                    part[r] += __shfl_xor(part[r], off, 64);
            }
            if (l15 == m) {
                f32x4 v4 = { part[0] + b2v, part[1] + b2v,
                             part[2] + b2v, part[3] + b2v };
                *reinterpret_cast<f32x4*>(&out[ebase + m * 16 + lg * 4]) = v4;
            }
        }
    }
}

extern "C" void kernel_launch(void* const* d_in, const int* in_sizes, int n_in,
                              void* d_out, int out_size, void* d_ws, size_t ws_size,
                              hipStream_t stream) {
    const float* x_src  = (const float*)d_in[0];
    const float* x_dst  = (const float*)d_in[1];
    const int*   sidx   = (const int*)d_in[2];
    const int*   didx   = (const int*)d_in[3];
    const float* W1     = (const float*)d_in[4];
    const float* b1     = (const float*)d_in[5];
    const float* W2     = (const float*)d_in[6];
    const float* b2     = (const float*)d_in[7];
    float* out = (float*)d_out;

    const int nEdges = in_sizes[2];
    const int nNodes = in_sizes[0] / HF;

    const size_t uvsz   = (size_t)2 * nNodes * HF;                  // elems
    const size_t needed = uvsz * sizeof(__bf16) + 64 * 1024;        // u+v+wf
    if (ws_size >= needed && (nNodes & 15) == 0) {
        __bf16* u  = (__bf16*)d_ws;
        __bf16* v  = u + (size_t)nNodes * HF;
        __bf16* wf = u + uvsz;

        w1_repack<<<2, 256, 0, stream>>>(W1, wf);

        node_precompute13<<<256, 512, 0, stream>>>(
            x_src, x_dst, wf, u, v, nNodes);

        const int egrid = (nEdges + 127) / 128;
        edge_score_kernel<<<egrid, 256, 0, stream>>>(
            u, v, sidx, didx, W2, b1, b2, out, nEdges);
    } else {
        edge_mlp_kernel<<<512, 256, 0, stream>>>(
            x_src, x_dst, sidx, didx, W1, b1, W2, b2, out, nEdges);
    }
}

// Round 13
// 80.547 us; speedup vs baseline: 1.0951x; 1.0208x over previous
//
#include <hip/hip_runtime.h>
#include <hip/hip_bf16.h>

typedef __bf16 bf16x8 __attribute__((ext_vector_type(8)));
typedef __bf16 bf16x4 __attribute__((ext_vector_type(4)));
typedef float  f32x4  __attribute__((ext_vector_type(4)));

#define HF 128          // hidden dim
#define W1K 256         // W1 inner dim (2H)

// ========== Kernel 0: one-time repack W1 fp32 -> bf16 MFMA-A-fragment order
// wf layout: [h][f=mt*4+kk][lane][8 bf16]; frag = W[h][mt*16+l15][kk*32+lg*8..+8]
__global__ __launch_bounds__(256) void w1_repack(
    const float* __restrict__ W1, __bf16* __restrict__ wf)
{
    const int h    = blockIdx.x;        // 0 -> A (u), 1 -> B (v)
    const int tid  = threadIdx.x;
    const int lane = tid & 63;
    const int wid  = tid >> 6;
    const int l15  = lane & 15;
    const int lg   = lane >> 4;

    for (int f = wid; f < 32; f += 4) {
        const int mt = f >> 2;
        const int kk = f & 3;
        const float* p = W1 + h * HF + (size_t)(mt * 16 + l15) * W1K
                       + kk * 32 + lg * 8;
        f32x4 a = *reinterpret_cast<const f32x4*>(p);
        f32x4 b = *reinterpret_cast<const f32x4*>(p + 4);
        bf16x8 w8;
        #pragma unroll
        for (int i = 0; i < 4; ++i) {
            w8[i]     = (__bf16)a[i];
            w8[i + 4] = (__bf16)b[i];
        }
        *reinterpret_cast<bf16x8*>(wf + ((size_t)(h * 32 + f) * 64 + lane) * 8) = w8;
    }
}

// ====== Kernel 1 (v14): reg-W + depth-2 async pipeline (triple buffer) =====
// u[n] = A . x_src[n],  v[n] = B . x_dst[n]   (b1 added in k2)
// R12: k1 ~33us at ~3.1 TB/s logical reads. Discriminating experiment:
// depth-2 prefetch (8-node tiles, 3 private LDS bufs/wave). Counted vmcnt,
// exact queue model (issue order per iter: STAGE L(k+2) ... stores S(k)):
//   steady  : [L(k), S(k-2), L(k+1), S(k-1), L(k+2)] -> vmcnt(16) drains L(k)
//   no-ahead: vmcnt(12); last iter: vmcnt(8); iter0: 8/4/0 (no prior stores).
// If dur unchanged vs v13 -> L3/fabric BW wall confirmed (not latency).
__global__ __launch_bounds__(512, 1) void node_precompute14(
    const float* __restrict__ x_src, const float* __restrict__ x_dst,
    const __bf16* __restrict__ wf,
    __bf16* __restrict__ u, __bf16* __restrict__ v, int nNodes)
{
    __shared__ __align__(16) float xlds[8][3][1024];   // 8 waves x 3 x 4 KiB

    const int tid  = threadIdx.x;
    const int lane = tid & 63;
    const int wid  = tid >> 6;      // 0..7
    const int l15  = lane & 15;
    const int lg   = lane >> 4;

    const int h = wid & 1;          // waves alternate halves
    const float* __restrict__ xh = h ? x_dst : x_src;
    __bf16* __restrict__ oph = h ? v : u;

    // ---- one-time: this half's 32 W fragments into 128 VGPRs (L3-hot) ----
    bf16x8 wfrag[32];
    {
        const __bf16* wsrc = wf + ((size_t)h * 32 * 64 + lane) * 8;
        #pragma unroll
        for (int f = 0; f < 32; ++f)
            wfrag[f] = *reinterpret_cast<const bf16x8*>(wsrc + (size_t)f * 64 * 8);
    }

    const int nst    = nNodes >> 3;        // 12500 8-node subtiles (exact)
    const int stride = gridDim.x * 4;      // wave-slots per half

    // ---- async stage: subtile st -> xlds[wid][buf]; 4 x 16B per lane ----
    // granule G = i*64+lane in [0,256): row = G>>5 (0..7), q = G&31.
    // linear LDS dest; source pre-swizzled q^row (rule 21).
    auto STAGE = [&](int buf, int st) {
        float* dst0 = &xlds[wid][buf][0];
        #pragma unroll
        for (int i = 0; i < 4; ++i) {
            const int G   = i * 64 + lane;
            const int row = G >> 5;
            const int q   = G & 31;
            const int qs  = q ^ row;
            const int grow = min(st * 8 + row, nNodes - 1);
            const float* src = xh + (size_t)grow * HF + qs * 4;
            __builtin_amdgcn_global_load_lds(
                (const __attribute__((address_space(1))) void*)src,
                (__attribute__((address_space(3))) void*)(dst0 + (size_t)G * 4),
                16, 0, 0);
        }
    };

    int st = blockIdx.x * 4 + (wid >> 1);
    if (st >= nst) return;

    STAGE(0, st);
    if (st + stride < nst) STAGE(1, st + stride);

    int it = 0;
    int bcur = 0;
    const int row_l = l15 & 7;     // lanes 8..15 alias rows 0..7 (broadcast)
    while (st < nst) {
        const int st1 = st + stride;
        const int st2 = st + 2 * stride;
        const bool hn = (st1 < nst);
        const bool ha = (st2 < nst);
        if (ha) STAGE((bcur + 2) % 3, st2);

        if (it == 0) {
            if (ha)      asm volatile("s_waitcnt vmcnt(8)"  ::: "memory");
            else if (hn) asm volatile("s_waitcnt vmcnt(4)"  ::: "memory");
            else         asm volatile("s_waitcnt vmcnt(0)"  ::: "memory");
        } else {
            if (ha)      asm volatile("s_waitcnt vmcnt(16)" ::: "memory");
            else if (hn) asm volatile("s_waitcnt vmcnt(12)" ::: "memory");
            else         asm volatile("s_waitcnt vmcnt(8)"  ::: "memory");
        }
        __builtin_amdgcn_sched_barrier(0);

        f32x4 acc[8];
        #pragma unroll
        for (int mt = 0; mt < 8; ++mt) acc[mt] = (f32x4){0.f, 0.f, 0.f, 0.f};

        const float* xr = &xlds[wid][bcur][(size_t)row_l * 128];
        #pragma unroll
        for (int kk = 0; kk < 4; ++kk) {
            const int q0 = kk * 8 + lg * 2;
            f32x4 a0 = *reinterpret_cast<const f32x4*>(xr + ((q0)     ^ row_l) * 4);
            f32x4 a1 = *reinterpret_cast<const f32x4*>(xr + ((q0 + 1) ^ row_l) * 4);
            bf16x8 xb;
            #pragma unroll
            for (int i = 0; i < 4; ++i) {
                xb[i]     = (__bf16)a0[i];
                xb[i + 4] = (__bf16)a1[i];
            }
            #pragma unroll
            for (int mt = 0; mt < 8; ++mt)
                acc[mt] = __builtin_amdgcn_mfma_f32_16x16x32_bf16(
                    wfrag[mt * 4 + kk], xb, acc[mt], 0, 0, 0);
        }

        // store: node = st*8 + l15 (l15<8), channels mt*16 + lg*4 .. +4
        if (l15 < 8) {
            const int node = st * 8 + l15;
            __bf16* op = oph + (size_t)node * HF + lg * 4;
            #pragma unroll
            for (int mt = 0; mt < 8; ++mt) {
                bf16x4 o4;
                #pragma unroll
                for (int r = 0; r < 4; ++r) o4[r] = (__bf16)acc[mt][r];
                *reinterpret_cast<bf16x4*>(op + mt * 16) = o4;
            }
        }

        bcur = (bcur + 1) % 3;
        st = st1;
        ++it;
    }
}

// ================= Kernel 2: per-edge score (pure gather, 4 edges/sub) =====
// score[e] = W2 . relu(u[src[e]] + v[dst[e]] + b1) + b2
__global__ __launch_bounds__(256) void edge_score_kernel(
    const __bf16* __restrict__ u, const __bf16* __restrict__ v,
    const int* __restrict__ sidx, const int* __restrict__ didx,
    const float* __restrict__ W2, const float* __restrict__ b1,
    const float* __restrict__ b2,
    float* __restrict__ out, int nEdges)
{
    const int tid = threadIdx.x;
    const int sub = tid >> 4;        // 0..15
    const int l16 = tid & 15;

    const int ebase = blockIdx.x * 64 + sub;   // edges ebase + {0,16,32,48}

    float w2v[8], b1v[8];
    #pragma unroll
    for (int j = 0; j < 8; ++j) {
        w2v[j] = W2[l16 * 8 + j];
        b1v[j] = b1[l16 * 8 + j];
    }
    const float b2v = b2[0];

    int e[4], si[4], di[4];
    #pragma unroll
    for (int q = 0; q < 4; ++q) {
        e[q] = ebase + q * 16;
        const int c = min(e[q], nEdges - 1);
        si[q] = sidx[c];
        di[q] = didx[c];
    }

    bf16x8 uv[4], vv[4];
    #pragma unroll
    for (int q = 0; q < 4; ++q) {
        uv[q] = *reinterpret_cast<const bf16x8*>(u + (size_t)si[q] * HF + l16 * 8);
        vv[q] = *reinterpret_cast<const bf16x8*>(v + (size_t)di[q] * HF + l16 * 8);
    }

    float s[4] = {0.f, 0.f, 0.f, 0.f};
    #pragma unroll
    for (int q = 0; q < 4; ++q)
        #pragma unroll
        for (int j = 0; j < 8; ++j)
            s[q] += fmaxf((float)uv[q][j] + (float)vv[q][j] + b1v[j], 0.f) * w2v[j];

    #pragma unroll
    for (int off = 1; off < 16; off <<= 1)
        #pragma unroll
        for (int q = 0; q < 4; ++q)
            s[q] += __shfl_xor(s[q], off, 64);

    if (l16 == 0) {
        #pragma unroll
        for (int q = 0; q < 4; ++q)
            if (e[q] < nEdges) out[e[q]] = s[q] + b2v;
    }
}

// ================= Fallback: fused single kernel (round-1) =================
__global__ __launch_bounds__(256, 2) void edge_mlp_kernel(
    const float* __restrict__ x_src, const float* __restrict__ x_dst,
    const int*   __restrict__ src_idx, const int* __restrict__ dst_idx,
    const float* __restrict__ W1, const float* __restrict__ b1,
    const float* __restrict__ W2, const float* __restrict__ b2,
    float* __restrict__ out, int nEdges)
{
    __shared__ __align__(16) __bf16 w1lds[64 * 64 * 8];

    const int tid  = threadIdx.x;
    const int lane = tid & 63;
    const int wid  = tid >> 6;
    const int l15  = lane & 15;
    const int lg   = lane >> 4;

    for (int p = wid; p < 64; p += 4) {
        const int n   = p >> 3;
        const int kk  = p & 7;
        const float* src = W1 + (n * 16 + l15) * W1K + kk * 32 + lg * 8;
        bf16x8 w8;
        #pragma unroll
        for (int i = 0; i < 8; ++i) w8[i] = (__bf16)src[i];
        *reinterpret_cast<bf16x8*>(&w1lds[(p * 64 + lane) * 8]) = w8;
    }
    __syncthreads();

    float w2v[8], b1v[8];
    #pragma unroll
    for (int n = 0; n < 8; ++n) {
        w2v[n] = W2[n * 16 + l15];
        b1v[n] = b1[n * 16 + l15];
    }
    const float b2v = b2[0];

    const int ntiles = nEdges / 256;
    for (int t = blockIdx.x; t < ntiles; t += gridDim.x) {
        const int ebase = t * 256 + wid * 64;

        const float* srow[4];
        const float* drow[4];
        #pragma unroll
        for (int m = 0; m < 4; ++m) {
            const int e  = ebase + m * 16 + l15;
            srow[m] = x_src + (size_t)src_idx[e] * HF + lg * 8;
            drow[m] = x_dst + (size_t)dst_idx[e] * HF + lg * 8;
        }

        f32x4 acc[4][8];
        #pragma unroll
        for (int m = 0; m < 4; ++m)
            #pragma unroll
            for (int n = 0; n < 8; ++n)
                acc[m][n] = (f32x4){0.f, 0.f, 0.f, 0.f};

        #pragma unroll
        for (int kk = 0; kk < 8; ++kk) {
            bf16x8 a[4];
            #pragma unroll
            for (int m = 0; m < 4; ++m) {
                const float* p = (kk < 4) ? (srow[m] + kk * 32)
                                          : (drow[m] + (kk - 4) * 32);
                f32x4 u0 = *reinterpret_cast<const f32x4*>(p);
                f32x4 u1 = *reinterpret_cast<const f32x4*>(p + 4);
                bf16x8 av;
                #pragma unroll
                for (int i = 0; i < 4; ++i) {
                    av[i]     = (__bf16)u0[i];
                    av[i + 4] = (__bf16)u1[i];
                }
                a[m] = av;
            }
            #pragma unroll
            for (int n = 0; n < 8; ++n) {
                bf16x8 bfrag = *reinterpret_cast<const bf16x8*>(
                    &w1lds[((n * 8 + kk) * 64 + lane) * 8]);
                #pragma unroll
                for (int m = 0; m < 4; ++m) {
                    acc[m][n] = __builtin_amdgcn_mfma_f32_16x16x32_bf16(
                        a[m], bfrag, acc[m][n], 0, 0, 0);
                }
            }
        }

        #pragma unroll
        for (int m = 0; m < 4; ++m) {
            float part[4];
            #pragma unroll
            for (int r = 0; r < 4; ++r) {
                float s = 0.f;
                #pragma unroll
                for (int n = 0; n < 8; ++n) {
                    float hv = acc[m][n][r] + b1v[n];
                    s += fmaxf(hv, 0.f) * w2v[n];
                }
                part[r] = s;
            }
            #pragma unroll
            for (int off = 1; off < 16; off <<= 1) {
                #pragma unroll
                for (int r = 0; r < 4; ++r)
                    part[r] += __shfl_xor(part[r], off, 64);
            }
            if (l15 == m) {
                f32x4 v4 = { part[0] + b2v, part[1] + b2v,
                             part[2] + b2v, part[3] + b2v };
                *reinterpret_cast<f32x4*>(&out[ebase + m * 16 + lg * 4]) = v4;
            }
        }
    }
}

extern "C" void kernel_launch(void* const* d_in, const int* in_sizes, int n_in,
                              void* d_out, int out_size, void* d_ws, size_t ws_size,
                              hipStream_t stream) {
    const float* x_src  = (const float*)d_in[0];
    const float* x_dst  = (const float*)d_in[1];
    const int*   sidx   = (const int*)d_in[2];
    const int*   didx   = (const int*)d_in[3];
    const float* W1     = (const float*)d_in[4];
    const float* b1     = (const float*)d_in[5];
    const float* W2     = (const float*)d_in[6];
    const float* b2     = (const float*)d_in[7];
    float* out = (float*)d_out;

    const int nEdges = in_sizes[2];
    const int nNodes = in_sizes[0] / HF;

    const size_t uvsz   = (size_t)2 * nNodes * HF;                  // elems
    const size_t needed = uvsz * sizeof(__bf16) + 64 * 1024;        // u+v+wf
    if (ws_size >= needed && (nNodes & 7) == 0) {
        __bf16* u  = (__bf16*)d_ws;
        __bf16* v  = u + (size_t)nNodes * HF;
        __bf16* wf = u + uvsz;

        w1_repack<<<2, 256, 0, stream>>>(W1, wf);

        node_precompute14<<<256, 512, 0, stream>>>(
            x_src, x_dst, wf, u, v, nNodes);

        const int egrid = (nEdges + 63) / 64;
        edge_score_kernel<<<egrid, 256, 0, stream>>>(
            u, v, sidx, didx, W2, b1, b2, out, nEdges);
    } else {
        edge_mlp_kernel<<<512, 256, 0, stream>>>(
            x_src, x_dst, sidx, didx, W1, b1, W2, b2, out, nEdges);
    }
}